// Round 1
// baseline (585.166 us; speedup 1.0000x reference)
//
#include <hip/hip_runtime.h>
#include <math.h>

#define NE 8
#define NH 2048
#define NI 1024
#define NT 512
#define NTOPK 2
#define NR 16
#define NGROUP 64
#define NPAIR (NT*NTOPK)   // 1024

typedef short bf16x8 __attribute__((ext_vector_type(8)));
typedef float f32x16 __attribute__((ext_vector_type(16)));
typedef unsigned int u32;

#define MFMA32 __builtin_amdgcn_mfma_f32_32x32x16_bf16

__device__ const float NF4_TAB[16] = {
    -1.0f, -0.6961928009986877f, -0.5250730514526367f, -0.39491748809814453f,
    -0.28444138169288635f, -0.18477343022823334f, -0.09105003625154495f, 0.0f,
    0.07958029955625534f, 0.16093020141124725f, 0.24611230194568634f,
    0.33791524171829224f, 0.44070982933044434f, 0.5626170039176941f,
    0.7229568362236328f, 1.0f};

// ---------------- workspace layout (bytes) ----------------
#define OFF_EXPOFF 0         // int[16]
#define OFF_TOK    256       // int[1024]
#define OFF_EXP    4352      // int[1024]
#define OFF_W      8448      // float[1024]
#define OFF_XAG    12544     // ushort[1024*16] bf16
#define OFF_XAU    45312     // ushort[1024*16]
#define OFF_HA     78080     // ushort[1024*16]
#define OFF_XB     131072    // ushort[512*2048] bf16 x (2 MB)
#define OFF_GU     2228224   // ushort[2*1024*1024] gate|up results (4 MB)
#define OFF_HBUF   6422528   // ushort[1024*1024] bf16 h (2 MB)

__device__ inline u32 f2bf(float f) {
    return (__float_as_uint(f) + 0x8000u) >> 16;
}
__device__ inline u32 bfpack2(float a, float b) {
    return ((__float_as_uint(a) + 0x8000u) >> 16) |
           ((__float_as_uint(b) + 0x8000u) & 0xFFFF0000u);
}
__device__ inline bf16x8 asbf(uint4 w) {
    union { uint4 u; bf16x8 b; } c; c.u = w; return c.b;
}
__device__ inline bf16x8 bfzero() { return asbf(make_uint4(0,0,0,0)); }
__device__ inline float bf2f(u32 v) { return __uint_as_float(v << 16); }

// async global->LDS: per-lane global addr, LDS dest = wave-uniform base + lane*16
__device__ __forceinline__ void stage16(const void* g, void* l) {
    __builtin_amdgcn_global_load_lds(
        (const __attribute__((address_space(1))) u32*)g,
        (__attribute__((address_space(3))) u32*)l, 16, 0, 0);
}

// single-wave pipeline waits; each K-step issues 8 VMEM ops (4 gll code +
// 4 global->reg A loads). vmcnt(16) = allow 2 steps in flight, step-s landed.
#define WAITV16() asm volatile("s_waitcnt vmcnt(16)" ::: "memory")
#define WAITV8()  asm volatile("s_waitcnt vmcnt(8)" ::: "memory")
#define WAITV0()  asm volatile("s_waitcnt vmcnt(0)" ::: "memory")

// -------- kernel 1: routing compaction --------
__global__ __launch_bounds__(1024) void k_route(const int* __restrict__ idx,
                                                const float* __restrict__ w,
                                                int* expert_off, int* ptok,
                                                int* pexp, float* pw) {
    __shared__ int cnt[NE], off[NE + 1], cur[NE];
    int tid = threadIdx.x;
    if (tid < NE) cnt[tid] = 0;
    __syncthreads();
    int e = idx[tid];
    float wt = w[tid];
    int t = tid >> 1;
    atomicAdd(&cnt[e], 1);
    __syncthreads();
    if (tid == 0) {
        off[0] = 0;
        for (int i = 0; i < NE; i++) off[i + 1] = off[i] + cnt[i];
    }
    __syncthreads();
    if (tid < NE) cur[tid] = off[tid];
    __syncthreads();
    int pos = atomicAdd(&cur[e], 1);
    ptok[pos] = t; pexp[pos] = e; pw[pos] = wt;
    if (tid <= NE) expert_off[tid] = off[tid];
}

// -------- kernel 2: x fp32 -> bf16 --------
__global__ __launch_bounds__(256) void k_xcvt(const float* __restrict__ x,
                                              unsigned short* __restrict__ xb) {
    int i = (blockIdx.x * 256 + threadIdx.x) * 8;
    float4 v0 = *(const float4*)(x + i);
    float4 v1 = *(const float4*)(x + i + 4);
    uint4 w;
    w.x = bfpack2(v0.x, v0.y); w.y = bfpack2(v0.z, v0.w);
    w.z = bfpack2(v1.x, v1.y); w.w = bfpack2(v1.z, v1.w);
    *(uint4*)(xb + i) = w;
}

// -------- kernel 3: xA_g[p][r], xA_u[p][r] --------
__global__ __launch_bounds__(256) void k_xA(const float* __restrict__ x,
                                            const float* __restrict__ gA,
                                            const float* __restrict__ uA,
                                            const int* __restrict__ ptok,
                                            const int* __restrict__ pexp,
                                            unsigned short* __restrict__ xAg,
                                            unsigned short* __restrict__ xAu) {
    int p = blockIdx.x;
    int t = ptok[p], e = pexp[p];
    int tid = threadIdx.x;
    int r = tid & 15, ch = tid >> 4;
    const float* xr = x + (size_t)t * NH;
    const float* gAr = gA + (size_t)e * NH * NR;
    const float* uAr = uA + (size_t)e * NH * NR;
    float sg = 0.f, su = 0.f;
    for (int j = ch * 128; j < ch * 128 + 128; ++j) {
        float xv = xr[j];
        sg += xv * gAr[j * NR + r];
        su += xv * uAr[j * NR + r];
    }
    __shared__ float red[2][16][16];
    red[0][ch][r] = sg; red[1][ch][r] = su;
    __syncthreads();
    for (int st = 8; st >= 1; st >>= 1) {
        if (ch < st) {
            red[0][ch][r] += red[0][ch + st][r];
            red[1][ch][r] += red[1][ch + st][r];
        }
        __syncthreads();
    }
    if (tid < 16) {
        xAg[p * NR + tid] = (unsigned short)f2bf(red[0][0][tid]);
        xAu[p * NR + tid] = (unsigned short)f2bf(red[1][0][tid]);
    }
}

// -------- kernel 4: gate OR up grouped GEMM --------
// 1 wave/block, tile 32 rows x 32 cols.
// A-operand: global->VGPR direct (per-lane identity vs old LDS roundtrip),
// 2 steps ahead in 3 reg buffers. Code: global_load_lds, 3 LDS buffers,
// 2 steps ahead. 8 VMEM ops/step -> vmcnt(16) counted waits, no barriers.
// LDS = 1K lut + 12K code + 4K sclb = 17408 B -> 9 blocks/CU (was 5).
__global__ __launch_bounds__(64) void k_gu(
    const unsigned short* __restrict__ xb,
    const int* __restrict__ gpk, const float* __restrict__ gsc,
    const int* __restrict__ upk, const float* __restrict__ usc,
    const float* __restrict__ gB, const float* __restrict__ uB,
    const unsigned short* __restrict__ xAg, const unsigned short* __restrict__ xAu,
    const int* __restrict__ expert_off, const int* __restrict__ ptok,
    unsigned short* __restrict__ gu)
{
    __shared__ u32 lut[256];                  // bf16-pair dequant LUT, 1 KB
    __shared__ u32 code[3][1024];             // 32 prows x 32 cols, 3x4 KB
    __shared__ float sclb[32][32];            // [step][col], 4 KB

    int lane = threadIdx.x;
    int q = lane >> 5, cw = lane & 31;
    for (int i = lane; i < 256; i += 64)
        lut[i] = bfpack2(NF4_TAB[i & 15], NF4_TAB[(i >> 4) & 15]);

    int e = blockIdx.x;
    int c0 = blockIdx.y * 32;
    int mat = blockIdx.z & 1;
    int rt = blockIdx.z >> 1;                 // row-tile 0..3
    const u32* pk = (const u32*)(mat ? upk : gpk);
    const float* scp = mat ? usc : gsc;
    const float* Bp = mat ? uB : gB;
    const unsigned short* xA = mat ? xAu : xAg;

    int off = expert_off[e];
    int cnt = expert_off[e + 1] - off;
    int colg = c0 + cw;
    const size_t pkb = (size_t)e * (NH / 2) * NI;

    // stage all 32 per-step scales once per block: sclb[s][col]
    {
        const float* sg = scp + (size_t)e * (NH / NGROUP) * NI + c0;
        #pragma unroll
        for (int g = 0; g < 4; ++g)
            stage16(sg + (size_t)(g * 8 + (lane >> 3)) * NI + ((lane & 7) << 2),
                    &sclb[g * 8][0]);
    }

    const int NS = NH / 64;                   // 32 K-steps
    for (int s0 = rt * 32; s0 < cnt; s0 += 128) {
        int rr = s0 + cw; if (rr > cnt - 1) rr = cnt - 1;
        u32 ro = (u32)ptok[off + rr] * (u32)NH;   // lanes l and l+32 identical
        const unsigned short* xr = xb + ro + (q << 3);  // A-frag base, this lane

        auto stageC = [&](int b, int s) {     // 4 global_load_lds (code tile)
            int kp0 = s << 5;
            #pragma unroll
            for (int g = 0; g < 4; ++g)
                stage16(pk + pkb + (size_t)(kp0 + (g << 3) + (lane >> 3)) * NI
                            + c0 + ((lane & 7) << 2),
                        &code[b][g << 8]);
        };
        auto loadA = [&](bf16x8* d, int s) {  // 4 global_load_dwordx4 -> regs
            #pragma unroll
            for (int ks = 0; ks < 4; ++ks)
                d[ks] = *(const bf16x8*)(xr + (s << 6) + (ks << 4));
        };

        bf16x8 A[3][4];
        f32x16 acc;
        #pragma unroll
        for (int i = 0; i < 16; ++i) acc[i] = 0.f;

        stageC(0, 0); loadA(A[0], 0);
        stageC(1, 1); loadA(A[1], 1);
        #pragma unroll
        for (int s = 0; s < NS; ++s) {
            if (s + 2 < NS) {
                stageC((s + 2) % 3, s + 2);
                loadA(A[(s + 2) % 3], s + 2);
                WAITV16();                    // step-s code+A landed, 2 in flight
            } else if (s + 1 < NS) {
                WAITV8();
            } else {
                WAITV0();
            }
            int b = s % 3;
            float scl = sclb[s][cw];
            f32x16 t;
            #pragma unroll
            for (int i = 0; i < 16; ++i) t[i] = 0.f;
            #pragma unroll
            for (int ks = 0; ks < 4; ++ks) {
                uint4 w4; u32* wp = &w4.x;
                #pragma unroll
                for (int i = 0; i < 4; ++i)
                    wp[i] = lut[code[b][(((ks << 3) + (q << 2) + i) << 5) + cw] & 255];
                t = MFMA32(A[b][ks], asbf(w4), t, 0, 0, 0);
            }
            #pragma unroll
            for (int i = 0; i < 16; ++i) acc[i] += scl * t[i];
        }

        // LoRA extension: += (x.A) . B  (K = 16)
        {
            bf16x8 la = bfzero();
            if (s0 + cw < cnt)
                la = *(const bf16x8*)(xA + (size_t)(off + s0 + cw) * NR + (q << 3));
            const float* Bq = Bp + ((size_t)e * NR + (q << 3)) * NI + colg;
            uint4 w4; u32* wp = &w4.x;
            #pragma unroll
            for (int i = 0; i < 4; ++i)
                wp[i] = bfpack2(Bq[(2 * i) * NI], Bq[(2 * i + 1) * NI]);
            acc = MFMA32(la, asbf(w4), acc, 0, 0, 0);
        }
        // epilogue: store bf16 tile. C row = (reg&3) + 8*(reg>>2) + 4*q
        unsigned short* outb = gu + (size_t)mat * NPAIR * NI;
        #pragma unroll
        for (int reg = 0; reg < 16; ++reg) {
            int rloc = (reg & 3) + 8 * (reg >> 2) + (q << 2);
            if (s0 + rloc < cnt)
                outb[(size_t)(off + s0 + rloc) * NI + colg] =
                    (unsigned short)f2bf(acc[reg]);
        }
    }
}

// -------- kernel 5: h = silu(gate)*up --------
__global__ __launch_bounds__(256) void k_swiglu(const unsigned short* __restrict__ gu,
                                                unsigned short* __restrict__ hbuf) {
    int i = (blockIdx.x * 256 + threadIdx.x) * 8;
    uint4 gv = *(const uint4*)(gu + i);
    uint4 uv = *(const uint4*)(gu + (size_t)NPAIR * NI + i);
    const u32* gp = &gv.x; const u32* up = &uv.x;
    uint4 hv; u32* hp = &hv.x;
    #pragma unroll
    for (int j = 0; j < 4; ++j) {
        float g0 = bf2f(gp[j] & 0xFFFFu), g1 = bf2f(gp[j] >> 16);
        float u0 = bf2f(up[j] & 0xFFFFu), u1 = bf2f(up[j] >> 16);
        float h0 = g0 * u0 / (1.f + __expf(-g0));
        float h1 = g1 * u1 / (1.f + __expf(-g1));
        hp[j] = bfpack2(h0, h1);
    }
    *(uint4*)(hbuf + i) = hv;
}

// -------- kernel 6: hA[p][r] = h . down_A --------
__global__ __launch_bounds__(256) void k_hA(const unsigned short* __restrict__ hbuf,
                                            const float* __restrict__ dA,
                                            const int* __restrict__ pexp,
                                            unsigned short* __restrict__ hA) {
    int p = blockIdx.x;
    int e = pexp[p];
    int tid = threadIdx.x;
    int r = tid & 15, ch = tid >> 4;
    const unsigned short* hr = hbuf + (size_t)p * NI;
    const float* dAr = dA + (size_t)e * NI * NR;
    float sv = 0.f;
    for (int j = ch * 64; j < ch * 64 + 64; ++j) {
        float hv = bf2f(hr[j]);
        sv += hv * dAr[j * NR + r];
    }
    __shared__ float red[16][16];
    red[ch][r] = sv;
    __syncthreads();
    for (int st = 8; st >= 1; st >>= 1) {
        if (ch < st) red[ch][r] += red[ch + st][r];
        __syncthreads();
    }
    if (tid < 16) hA[p * NR + tid] = (unsigned short)f2bf(red[0][tid]);
}

// -------- kernel 7: down GEMM (same pipeline as k_gu) + combine ----
// LDS = 1K lut + 12K code + 2K sclb = 15360 B -> 10 blocks/CU.
__global__ __launch_bounds__(64) void k_dn(
    const unsigned short* __restrict__ hbuf,
    const int* __restrict__ dpk, const float* __restrict__ dsc,
    const float* __restrict__ dB,
    const unsigned short* __restrict__ hA,
    const int* __restrict__ expert_off, const int* __restrict__ ptok,
    const float* __restrict__ pw,
    float* __restrict__ out)
{
    __shared__ u32 lut[256];
    __shared__ u32 code[3][1024];
    __shared__ float sclb[16][32];

    int lane = threadIdx.x;
    int q = lane >> 5, cw = lane & 31;
    for (int i = lane; i < 256; i += 64)
        lut[i] = bfpack2(NF4_TAB[i & 15], NF4_TAB[(i >> 4) & 15]);

    int e = blockIdx.x;
    int c0 = blockIdx.y * 32;
    int rt = blockIdx.z;                      // 0..3
    const u32* pk = (const u32*)dpk;

    int off = expert_off[e];
    int cnt = expert_off[e + 1] - off;
    int colg = c0 + cw;
    const size_t pkb = (size_t)e * (NI / 2) * NH;

    {
        const float* sg = dsc + (size_t)e * (NI / NGROUP) * NH + c0;
        #pragma unroll
        for (int g = 0; g < 2; ++g)
            stage16(sg + (size_t)(g * 8 + (lane >> 3)) * NH + ((lane & 7) << 2),
                    &sclb[g * 8][0]);
    }

    const int NS = NI / 64;                   // 16 K-steps
    for (int s0 = rt * 32; s0 < cnt; s0 += 128) {
        int rr = s0 + cw; if (rr > cnt - 1) rr = cnt - 1;
        u32 ro = (u32)(off + rr) * (u32)NI;   // compact h rows
        const unsigned short* hr = hbuf + ro + (q << 3);

        auto stageC = [&](int b, int s) {
            int kp0 = s << 5;
            #pragma unroll
            for (int g = 0; g < 4; ++g)
                stage16(pk + pkb + (size_t)(kp0 + (g << 3) + (lane >> 3)) * NH
                            + c0 + ((lane & 7) << 2),
                        &code[b][g << 8]);
        };
        auto loadA = [&](bf16x8* d, int s) {
            #pragma unroll
            for (int ks = 0; ks < 4; ++ks)
                d[ks] = *(const bf16x8*)(hr + (s << 6) + (ks << 4));
        };

        bf16x8 A[3][4];
        f32x16 acc;
        #pragma unroll
        for (int i = 0; i < 16; ++i) acc[i] = 0.f;

        stageC(0, 0); loadA(A[0], 0);
        stageC(1, 1); loadA(A[1], 1);
        #pragma unroll
        for (int s = 0; s < NS; ++s) {
            if (s + 2 < NS) {
                stageC((s + 2) % 3, s + 2);
                loadA(A[(s + 2) % 3], s + 2);
                WAITV16();
            } else if (s + 1 < NS) {
                WAITV8();
            } else {
                WAITV0();
            }
            int b = s % 3;
            float scl = sclb[s][cw];
            f32x16 t;
            #pragma unroll
            for (int i = 0; i < 16; ++i) t[i] = 0.f;
            #pragma unroll
            for (int ks = 0; ks < 4; ++ks) {
                uint4 w4; u32* wp = &w4.x;
                #pragma unroll
                for (int i = 0; i < 4; ++i)
                    wp[i] = lut[code[b][(((ks << 3) + (q << 2) + i) << 5) + cw] & 255];
                t = MFMA32(A[b][ks], asbf(w4), t, 0, 0, 0);
            }
            #pragma unroll
            for (int i = 0; i < 16; ++i) acc[i] += scl * t[i];
        }

        // LoRA extension: += (h.down_A) . down_B (K = 16)
        {
            bf16x8 la = bfzero();
            if (s0 + cw < cnt)
                la = *(const bf16x8*)(hA + (size_t)(off + s0 + cw) * NR + (q << 3));
            const float* Bq = dB + ((size_t)e * NR + (q << 3)) * NH + colg;
            uint4 w4; u32* wp = &w4.x;
            #pragma unroll
            for (int i = 0; i < 4; ++i)
                wp[i] = bfpack2(Bq[(2 * i) * NH], Bq[(2 * i + 1) * NH]);
            acc = MFMA32(la, asbf(w4), acc, 0, 0, 0);
        }
        // epilogue: weighted atomic combine
        #pragma unroll
        for (int reg = 0; reg < 16; ++reg) {
            int rloc = (reg & 3) + 8 * (reg >> 2) + (q << 2);
            if (s0 + rloc < cnt) {
                int p = off + s0 + rloc;
                atomicAdd(&out[(size_t)ptok[p] * NH + colg], acc[reg] * pw[p]);
            }
        }
    }
}

extern "C" void kernel_launch(void* const* d_in, const int* in_sizes, int n_in,
                              void* d_out, int out_size, void* d_ws,
                              size_t ws_size, hipStream_t stream) {
    const float* x = (const float*)d_in[0];
    const int* topk_idx = (const int*)d_in[1];
    const float* topk_w = (const float*)d_in[2];
    const int* gate_packed = (const int*)d_in[3];
    const float* gate_scales = (const float*)d_in[4];
    const int* up_packed = (const int*)d_in[5];
    const float* up_scales = (const float*)d_in[6];
    const int* down_packed = (const int*)d_in[7];
    const float* down_scales = (const float*)d_in[8];
    const float* gate_A = (const float*)d_in[9];
    const float* gate_B = (const float*)d_in[10];
    const float* up_A = (const float*)d_in[11];
    const float* up_B = (const float*)d_in[12];
    const float* down_A = (const float*)d_in[13];
    const float* down_B = (const float*)d_in[14];
    float* out = (float*)d_out;

    char* ws = (char*)d_ws;
    int* expert_off = (int*)(ws + OFF_EXPOFF);
    int* ptok = (int*)(ws + OFF_TOK);
    int* pexp = (int*)(ws + OFF_EXP);
    float* pw = (float*)(ws + OFF_W);
    unsigned short* xAg = (unsigned short*)(ws + OFF_XAG);
    unsigned short* xAu = (unsigned short*)(ws + OFF_XAU);
    unsigned short* hA = (unsigned short*)(ws + OFF_HA);
    unsigned short* xb = (unsigned short*)(ws + OFF_XB);
    unsigned short* gu = (unsigned short*)(ws + OFF_GU);
    unsigned short* hbuf = (unsigned short*)(ws + OFF_HBUF);

    hipMemsetAsync(d_out, 0, (size_t)NT * NH * sizeof(float), stream);

    k_route<<<1, 1024, 0, stream>>>(topk_idx, topk_w, expert_off, ptok, pexp, pw);
    k_xcvt<<<(NT * NH) / (256 * 8), 256, 0, stream>>>(x, xb);
    k_xA<<<NPAIR, 256, 0, stream>>>(x, gate_A, up_A, ptok, pexp, xAg, xAu);
    k_gu<<<dim3(NE, NI / 32, 8), 64, 0, stream>>>(
        xb, gate_packed, gate_scales, up_packed, up_scales, gate_B, up_B,
        xAg, xAu, expert_off, ptok, gu);
    k_swiglu<<<(NPAIR * NI) / (256 * 8), 256, 0, stream>>>(gu, hbuf);
    k_hA<<<NPAIR, 256, 0, stream>>>(hbuf, down_A, pexp, hA);
    k_dn<<<dim3(NE, NH / 32, 4), 64, 0, stream>>>(
        hbuf, down_packed, down_scales, down_B, hA, expert_off, ptok, pw, out);
}

// Round 2
// 274.964 us; speedup vs baseline: 2.1282x; 2.1282x over previous
//
#include <hip/hip_runtime.h>
#include <math.h>

#define NE 8
#define NH 2048
#define NI 1024
#define NT 512
#define NTOPK 2
#define NR 16
#define NGROUP 64
#define NPAIR (NT*NTOPK)   // 1024

typedef short bf16x8 __attribute__((ext_vector_type(8)));
typedef float f32x16 __attribute__((ext_vector_type(16)));
typedef unsigned int u32;

#define MFMA32 __builtin_amdgcn_mfma_f32_32x32x16_bf16

__device__ const float NF4_TAB[16] = {
    -1.0f, -0.6961928009986877f, -0.5250730514526367f, -0.39491748809814453f,
    -0.28444138169288635f, -0.18477343022823334f, -0.09105003625154495f, 0.0f,
    0.07958029955625534f, 0.16093020141124725f, 0.24611230194568634f,
    0.33791524171829224f, 0.44070982933044434f, 0.5626170039176941f,
    0.7229568362236328f, 1.0f};

// ---------------- workspace layout (bytes) ----------------
#define OFF_EXPOFF 0         // int[16]
#define OFF_TOK    256       // int[1024]
#define OFF_EXP    4352      // int[1024]
#define OFF_W      8448      // float[1024]
#define OFF_XAG    12544     // ushort[1024*16] bf16
#define OFF_XAU    45312     // ushort[1024*16]
#define OFF_HA     78080     // ushort[1024*16]
#define OFF_XB     131072    // ushort[512*2048] bf16 x (2 MB)
#define OFF_GU     2228224   // ushort[2*1024*1024] gate|up results (4 MB)
#define OFF_HBUF   6422528   // ushort[1024*1024] bf16 h (2 MB)

__device__ inline u32 f2bf(float f) {
    return (__float_as_uint(f) + 0x8000u) >> 16;
}
__device__ inline u32 bfpack2(float a, float b) {
    return ((__float_as_uint(a) + 0x8000u) >> 16) |
           ((__float_as_uint(b) + 0x8000u) & 0xFFFF0000u);
}
__device__ inline bf16x8 asbf(uint4 w) {
    union { uint4 u; bf16x8 b; } c; c.u = w; return c.b;
}
__device__ inline bf16x8 bfzero() { return asbf(make_uint4(0,0,0,0)); }
__device__ inline float bf2f(u32 v) { return __uint_as_float(v << 16); }

// async global->LDS: per-lane global addr, LDS dest = wave-uniform base + lane*16
__device__ __forceinline__ void stage16(const void* g, void* l) {
    __builtin_amdgcn_global_load_lds(
        (const __attribute__((address_space(1))) u32*)g,
        (__attribute__((address_space(3))) u32*)l, 16, 0, 0);
}

// single-wave pipeline waits. One K-step bundle = 8 VMEM ops (4 gll code +
// 4 global->reg A loads); steady state keeps 2 bundles in flight.
// vmcnt(8) = oldest bundle landed; vmcnt(0) = drain (tail only).
#define WAITV8()  asm volatile("s_waitcnt vmcnt(8)" ::: "memory")
#define WAITV0()  asm volatile("s_waitcnt vmcnt(0)" ::: "memory")

// -------- kernel 1: routing compaction --------
__global__ __launch_bounds__(1024) void k_route(const int* __restrict__ idx,
                                                const float* __restrict__ w,
                                                int* expert_off, int* ptok,
                                                int* pexp, float* pw) {
    __shared__ int cnt[NE], off[NE + 1], cur[NE];
    int tid = threadIdx.x;
    if (tid < NE) cnt[tid] = 0;
    __syncthreads();
    int e = idx[tid];
    float wt = w[tid];
    int t = tid >> 1;
    atomicAdd(&cnt[e], 1);
    __syncthreads();
    if (tid == 0) {
        off[0] = 0;
        for (int i = 0; i < NE; i++) off[i + 1] = off[i] + cnt[i];
    }
    __syncthreads();
    if (tid < NE) cur[tid] = off[tid];
    __syncthreads();
    int pos = atomicAdd(&cur[e], 1);
    ptok[pos] = t; pexp[pos] = e; pw[pos] = wt;
    if (tid <= NE) expert_off[tid] = off[tid];
}

// -------- kernel 2: x fp32 -> bf16 --------
__global__ __launch_bounds__(256) void k_xcvt(const float* __restrict__ x,
                                              unsigned short* __restrict__ xb) {
    int i = (blockIdx.x * 256 + threadIdx.x) * 8;
    float4 v0 = *(const float4*)(x + i);
    float4 v1 = *(const float4*)(x + i + 4);
    uint4 w;
    w.x = bfpack2(v0.x, v0.y); w.y = bfpack2(v0.z, v0.w);
    w.z = bfpack2(v1.x, v1.y); w.w = bfpack2(v1.z, v1.w);
    *(uint4*)(xb + i) = w;
}

// -------- kernel 3: xA_g[p][r], xA_u[p][r] --------
__global__ __launch_bounds__(256) void k_xA(const float* __restrict__ x,
                                            const float* __restrict__ gA,
                                            const float* __restrict__ uA,
                                            const int* __restrict__ ptok,
                                            const int* __restrict__ pexp,
                                            unsigned short* __restrict__ xAg,
                                            unsigned short* __restrict__ xAu) {
    int p = blockIdx.x;
    int t = ptok[p], e = pexp[p];
    int tid = threadIdx.x;
    int r = tid & 15, ch = tid >> 4;
    const float* xr = x + (size_t)t * NH;
    const float* gAr = gA + (size_t)e * NH * NR;
    const float* uAr = uA + (size_t)e * NH * NR;
    float sg = 0.f, su = 0.f;
    for (int j = ch * 128; j < ch * 128 + 128; ++j) {
        float xv = xr[j];
        sg += xv * gAr[j * NR + r];
        su += xv * uAr[j * NR + r];
    }
    __shared__ float red[2][16][16];
    red[0][ch][r] = sg; red[1][ch][r] = su;
    __syncthreads();
    for (int st = 8; st >= 1; st >>= 1) {
        if (ch < st) {
            red[0][ch][r] += red[0][ch + st][r];
            red[1][ch][r] += red[1][ch + st][r];
        }
        __syncthreads();
    }
    if (tid < 16) {
        xAg[p * NR + tid] = (unsigned short)f2bf(red[0][0][tid]);
        xAu[p * NR + tid] = (unsigned short)f2bf(red[1][0][tid]);
    }
}

// -------- kernel 4: gate OR up grouped GEMM --------
// 1 wave/block, tile 32 rows x 32 cols.
// A-operand: global->VGPR direct into TWO STATICALLY-NAMED reg buffers
// Aa/Ab (the MFMA A-frag address is a per-lane identity of the old LDS
// staging, so no LDS round-trip is needed). Code tile: global_load_lds into
// two named LDS buffers code0/code1. s-loop manually unrolled x2 so every
// buffer index is compile-time static (rule #20: runtime-indexed
// ext_vector arrays go to scratch -- the round-1 regression).
// Issue-after-compute double-buffer, vmcnt(8)-gated, no barriers.
// LDS = 1K lut + 8K code + 4K sclb = 13312 B -> 12 blocks/CU (grid needs 8).
__global__ __launch_bounds__(64, 3) void k_gu(
    const unsigned short* __restrict__ xb,
    const int* __restrict__ gpk, const float* __restrict__ gsc,
    const int* __restrict__ upk, const float* __restrict__ usc,
    const float* __restrict__ gB, const float* __restrict__ uB,
    const unsigned short* __restrict__ xAg, const unsigned short* __restrict__ xAu,
    const int* __restrict__ expert_off, const int* __restrict__ ptok,
    unsigned short* __restrict__ gu)
{
    __shared__ u32 lut[256];                  // bf16-pair dequant LUT, 1 KB
    __shared__ u32 code0[1024];               // 32 prows x 32 cols, 4 KB
    __shared__ u32 code1[1024];               // 4 KB
    __shared__ float sclb[32][32];            // [step][col], 4 KB

    int lane = threadIdx.x;
    int q = lane >> 5, cw = lane & 31;
    for (int i = lane; i < 256; i += 64)
        lut[i] = bfpack2(NF4_TAB[i & 15], NF4_TAB[(i >> 4) & 15]);

    int e = blockIdx.x;
    int c0 = blockIdx.y * 32;
    int mat = blockIdx.z & 1;
    int rt = blockIdx.z >> 1;                 // row-tile 0..3
    const u32* pk = (const u32*)(mat ? upk : gpk);
    const float* scp = mat ? usc : gsc;
    const float* Bp = mat ? uB : gB;
    const unsigned short* xA = mat ? xAu : xAg;

    int off = expert_off[e];
    int cnt = expert_off[e + 1] - off;
    int colg = c0 + cw;
    const size_t pkb = (size_t)e * (NH / 2) * NI;

    // stage all 32 per-step scales once per block: sclb[s][col]
    {
        const float* sg = scp + (size_t)e * (NH / NGROUP) * NI + c0;
        #pragma unroll
        for (int g = 0; g < 4; ++g)
            stage16(sg + (size_t)(g * 8 + (lane >> 3)) * NI + ((lane & 7) << 2),
                    &sclb[g * 8][0]);
    }

    const int NS = NH / 64;                   // 32 K-steps (even)
    for (int s0 = rt * 32; s0 < cnt; s0 += 128) {
        int rr = s0 + cw; if (rr > cnt - 1) rr = cnt - 1;
        u32 ro = (u32)ptok[off + rr] * (u32)NH;   // lanes l and l+32 identical
        const unsigned short* xr = xb + ro + (q << 3);  // A-frag base, this lane

        auto stageC = [&](u32* cb, int s) {   // 4 global_load_lds (code tile)
            int kp0 = s << 5;
            #pragma unroll
            for (int g = 0; g < 4; ++g)
                stage16(pk + pkb + (size_t)(kp0 + (g << 3) + (lane >> 3)) * NI
                            + c0 + ((lane & 7) << 2),
                        cb + (g << 8));
        };
        auto loadA = [&](bf16x8* d, int s) {  // 4 global_load_dwordx4 -> regs
            #pragma unroll
            for (int ks = 0; ks < 4; ++ks)
                d[ks] = *(const bf16x8*)(xr + (s << 6) + (ks << 4));
        };

        bf16x8 Aa[4], Ab[4];                  // static-indexed only (unrolled ks)
        f32x16 acc;
        #pragma unroll
        for (int i = 0; i < 16; ++i) acc[i] = 0.f;

        auto compute = [&](const u32* cb, const bf16x8* Ar, float scl) {
            f32x16 t;
            #pragma unroll
            for (int i = 0; i < 16; ++i) t[i] = 0.f;
            #pragma unroll
            for (int ks = 0; ks < 4; ++ks) {
                uint4 w4; u32* wp = &w4.x;
                #pragma unroll
                for (int i = 0; i < 4; ++i)
                    wp[i] = lut[cb[(((ks << 3) + (q << 2) + i) << 5) + cw] & 255];
                t = MFMA32(Ar[ks], asbf(w4), t, 0, 0, 0);
            }
            #pragma unroll
            for (int i = 0; i < 16; ++i) acc[i] += scl * t[i];
        };

        stageC(code0, 0); loadA(Aa, 0);
        stageC(code1, 1); loadA(Ab, 1);
        for (int s = 0; s < NS; s += 2) {
            // step s (code0 / Aa)
            WAITV8();                         // bundle(s) landed
            compute(code0, Aa, sclb[s][cw]);
            if (s + 2 < NS) { stageC(code0, s + 2); loadA(Aa, s + 2); }
            // step s+1 (code1 / Ab)
            if (s + 3 < NS) WAITV8(); else WAITV0();
            compute(code1, Ab, sclb[s + 1][cw]);
            if (s + 3 < NS) { stageC(code1, s + 3); loadA(Ab, s + 3); }
        }

        // LoRA extension: += (x.A) . B  (K = 16)
        {
            bf16x8 la = bfzero();
            if (s0 + cw < cnt)
                la = *(const bf16x8*)(xA + (size_t)(off + s0 + cw) * NR + (q << 3));
            const float* Bq = Bp + ((size_t)e * NR + (q << 3)) * NI + colg;
            uint4 w4; u32* wp = &w4.x;
            #pragma unroll
            for (int i = 0; i < 4; ++i)
                wp[i] = bfpack2(Bq[(2 * i) * NI], Bq[(2 * i + 1) * NI]);
            acc = MFMA32(la, asbf(w4), acc, 0, 0, 0);
        }
        // epilogue: store bf16 tile. C row = (reg&3) + 8*(reg>>2) + 4*q
        unsigned short* outb = gu + (size_t)mat * NPAIR * NI;
        #pragma unroll
        for (int reg = 0; reg < 16; ++reg) {
            int rloc = (reg & 3) + 8 * (reg >> 2) + (q << 2);
            if (s0 + rloc < cnt)
                outb[(size_t)(off + s0 + rloc) * NI + colg] =
                    (unsigned short)f2bf(acc[reg]);
        }
    }
}

// -------- kernel 5: h = silu(gate)*up --------
__global__ __launch_bounds__(256) void k_swiglu(const unsigned short* __restrict__ gu,
                                                unsigned short* __restrict__ hbuf) {
    int i = (blockIdx.x * 256 + threadIdx.x) * 8;
    uint4 gv = *(const uint4*)(gu + i);
    uint4 uv = *(const uint4*)(gu + (size_t)NPAIR * NI + i);
    const u32* gp = &gv.x; const u32* up = &uv.x;
    uint4 hv; u32* hp = &hv.x;
    #pragma unroll
    for (int j = 0; j < 4; ++j) {
        float g0 = bf2f(gp[j] & 0xFFFFu), g1 = bf2f(gp[j] >> 16);
        float u0 = bf2f(up[j] & 0xFFFFu), u1 = bf2f(up[j] >> 16);
        float h0 = g0 * u0 / (1.f + __expf(-g0));
        float h1 = g1 * u1 / (1.f + __expf(-g1));
        hp[j] = bfpack2(h0, h1);
    }
    *(uint4*)(hbuf + i) = hv;
}

// -------- kernel 6: hA[p][r] = h . down_A --------
__global__ __launch_bounds__(256) void k_hA(const unsigned short* __restrict__ hbuf,
                                            const float* __restrict__ dA,
                                            const int* __restrict__ pexp,
                                            unsigned short* __restrict__ hA) {
    int p = blockIdx.x;
    int e = pexp[p];
    int tid = threadIdx.x;
    int r = tid & 15, ch = tid >> 4;
    const unsigned short* hr = hbuf + (size_t)p * NI;
    const float* dAr = dA + (size_t)e * NI * NR;
    float sv = 0.f;
    for (int j = ch * 64; j < ch * 64 + 64; ++j) {
        float hv = bf2f(hr[j]);
        sv += hv * dAr[j * NR + r];
    }
    __shared__ float red[16][16];
    red[ch][r] = sv;
    __syncthreads();
    for (int st = 8; st >= 1; st >>= 1) {
        if (ch < st) red[ch][r] += red[ch + st][r];
        __syncthreads();
    }
    if (tid < 16) hA[p * NR + tid] = (unsigned short)f2bf(red[0][tid]);
}

// -------- kernel 7: down GEMM (same pipeline as k_gu) + combine ----
// LDS = 1K lut + 8K code + 2K sclb = 11264 B -> 14 blocks/CU (grid needs 8).
__global__ __launch_bounds__(64, 3) void k_dn(
    const unsigned short* __restrict__ hbuf,
    const int* __restrict__ dpk, const float* __restrict__ dsc,
    const float* __restrict__ dB,
    const unsigned short* __restrict__ hA,
    const int* __restrict__ expert_off, const int* __restrict__ ptok,
    const float* __restrict__ pw,
    float* __restrict__ out)
{
    __shared__ u32 lut[256];
    __shared__ u32 code0[1024];
    __shared__ u32 code1[1024];
    __shared__ float sclb[16][32];

    int lane = threadIdx.x;
    int q = lane >> 5, cw = lane & 31;
    for (int i = lane; i < 256; i += 64)
        lut[i] = bfpack2(NF4_TAB[i & 15], NF4_TAB[(i >> 4) & 15]);

    int e = blockIdx.x;
    int c0 = blockIdx.y * 32;
    int rt = blockIdx.z;                      // 0..3
    const u32* pk = (const u32*)dpk;

    int off = expert_off[e];
    int cnt = expert_off[e + 1] - off;
    int colg = c0 + cw;
    const size_t pkb = (size_t)e * (NI / 2) * NH;

    {
        const float* sg = dsc + (size_t)e * (NI / NGROUP) * NH + c0;
        #pragma unroll
        for (int g = 0; g < 2; ++g)
            stage16(sg + (size_t)(g * 8 + (lane >> 3)) * NH + ((lane & 7) << 2),
                    &sclb[g * 8][0]);
    }

    const int NS = NI / 64;                   // 16 K-steps (even)
    for (int s0 = rt * 32; s0 < cnt; s0 += 128) {
        int rr = s0 + cw; if (rr > cnt - 1) rr = cnt - 1;
        u32 ro = (u32)(off + rr) * (u32)NI;   // compact h rows
        const unsigned short* hr = hbuf + ro + (q << 3);

        auto stageC = [&](u32* cb, int s) {
            int kp0 = s << 5;
            #pragma unroll
            for (int g = 0; g < 4; ++g)
                stage16(pk + pkb + (size_t)(kp0 + (g << 3) + (lane >> 3)) * NH
                            + c0 + ((lane & 7) << 2),
                        cb + (g << 8));
        };
        auto loadA = [&](bf16x8* d, int s) {
            #pragma unroll
            for (int ks = 0; ks < 4; ++ks)
                d[ks] = *(const bf16x8*)(hr + (s << 6) + (ks << 4));
        };

        bf16x8 Aa[4], Ab[4];
        f32x16 acc;
        #pragma unroll
        for (int i = 0; i < 16; ++i) acc[i] = 0.f;

        auto compute = [&](const u32* cb, const bf16x8* Ar, float scl) {
            f32x16 t;
            #pragma unroll
            for (int i = 0; i < 16; ++i) t[i] = 0.f;
            #pragma unroll
            for (int ks = 0; ks < 4; ++ks) {
                uint4 w4; u32* wp = &w4.x;
                #pragma unroll
                for (int i = 0; i < 4; ++i)
                    wp[i] = lut[cb[(((ks << 3) + (q << 2) + i) << 5) + cw] & 255];
                t = MFMA32(Ar[ks], asbf(w4), t, 0, 0, 0);
            }
            #pragma unroll
            for (int i = 0; i < 16; ++i) acc[i] += scl * t[i];
        };

        stageC(code0, 0); loadA(Aa, 0);
        stageC(code1, 1); loadA(Ab, 1);
        for (int s = 0; s < NS; s += 2) {
            WAITV8();
            compute(code0, Aa, sclb[s][cw]);
            if (s + 2 < NS) { stageC(code0, s + 2); loadA(Aa, s + 2); }
            if (s + 3 < NS) WAITV8(); else WAITV0();
            compute(code1, Ab, sclb[s + 1][cw]);
            if (s + 3 < NS) { stageC(code1, s + 3); loadA(Ab, s + 3); }
        }

        // LoRA extension: += (h.down_A) . down_B (K = 16)
        {
            bf16x8 la = bfzero();
            if (s0 + cw < cnt)
                la = *(const bf16x8*)(hA + (size_t)(off + s0 + cw) * NR + (q << 3));
            const float* Bq = dB + ((size_t)e * NR + (q << 3)) * NH + colg;
            uint4 w4; u32* wp = &w4.x;
            #pragma unroll
            for (int i = 0; i < 4; ++i)
                wp[i] = bfpack2(Bq[(2 * i) * NH], Bq[(2 * i + 1) * NH]);
            acc = MFMA32(la, asbf(w4), acc, 0, 0, 0);
        }
        // epilogue: weighted atomic combine
        #pragma unroll
        for (int reg = 0; reg < 16; ++reg) {
            int rloc = (reg & 3) + 8 * (reg >> 2) + (q << 2);
            if (s0 + rloc < cnt) {
                int p = off + s0 + rloc;
                atomicAdd(&out[(size_t)ptok[p] * NH + colg], acc[reg] * pw[p]);
            }
        }
    }
}

extern "C" void kernel_launch(void* const* d_in, const int* in_sizes, int n_in,
                              void* d_out, int out_size, void* d_ws,
                              size_t ws_size, hipStream_t stream) {
    const float* x = (const float*)d_in[0];
    const int* topk_idx = (const int*)d_in[1];
    const float* topk_w = (const float*)d_in[2];
    const int* gate_packed = (const int*)d_in[3];
    const float* gate_scales = (const float*)d_in[4];
    const int* up_packed = (const int*)d_in[5];
    const float* up_scales = (const float*)d_in[6];
    const int* down_packed = (const int*)d_in[7];
    const float* down_scales = (const float*)d_in[8];
    const float* gate_A = (const float*)d_in[9];
    const float* gate_B = (const float*)d_in[10];
    const float* up_A = (const float*)d_in[11];
    const float* up_B = (const float*)d_in[12];
    const float* down_A = (const float*)d_in[13];
    const float* down_B = (const float*)d_in[14];
    float* out = (float*)d_out;

    char* ws = (char*)d_ws;
    int* expert_off = (int*)(ws + OFF_EXPOFF);
    int* ptok = (int*)(ws + OFF_TOK);
    int* pexp = (int*)(ws + OFF_EXP);
    float* pw = (float*)(ws + OFF_W);
    unsigned short* xAg = (unsigned short*)(ws + OFF_XAG);
    unsigned short* xAu = (unsigned short*)(ws + OFF_XAU);
    unsigned short* hA = (unsigned short*)(ws + OFF_HA);
    unsigned short* xb = (unsigned short*)(ws + OFF_XB);
    unsigned short* gu = (unsigned short*)(ws + OFF_GU);
    unsigned short* hbuf = (unsigned short*)(ws + OFF_HBUF);

    hipMemsetAsync(d_out, 0, (size_t)NT * NH * sizeof(float), stream);

    k_route<<<1, 1024, 0, stream>>>(topk_idx, topk_w, expert_off, ptok, pexp, pw);
    k_xcvt<<<(NT * NH) / (256 * 8), 256, 0, stream>>>(x, xb);
    k_xA<<<NPAIR, 256, 0, stream>>>(x, gate_A, up_A, ptok, pexp, xAg, xAu);
    k_gu<<<dim3(NE, NI / 32, 8), 64, 0, stream>>>(
        xb, gate_packed, gate_scales, up_packed, up_scales, gate_B, up_B,
        xAg, xAu, expert_off, ptok, gu);
    k_swiglu<<<(NPAIR * NI) / (256 * 8), 256, 0, stream>>>(gu, hbuf);
    k_hA<<<NPAIR, 256, 0, stream>>>(hbuf, down_A, pexp, hA);
    k_dn<<<dim3(NE, NH / 32, 4), 64, 0, stream>>>(
        hbuf, down_packed, down_scales, down_B, hA, expert_off, ptok, pw, out);
}